// Round 13
// baseline (3488.093 us; speedup 1.0000x reference)
//
#include <hip/hip_runtime.h>
#include <math.h>

// Problem constants (must match reference)
constexpr int B = 8, N = 32768, C = 3, H = 256, R = 64, NHID = 4;
constexpr int PTS   = 64;    // points per block
constexpr int BLOCK = 256;   // 64 o-lanes (4 outputs each) x 4 waves (16 pts each)
constexpr int PADA  = 260;   // LDS act row stride (multiple of 4 -> aligned float4)

// Workspace (floats), total ~9.46 MB (r7/r8/r12 layout, proven):
//   dwT : [NHID][B][H][H]  dW transposed [i][o]  (np-exact values)  = 2,097,152
//   wT  : [NHID][H][H]     W_hid transposed [i][o] (bit-exact copy) =   262,144
//   dw0 : [B][H][3]        layer-0 dW                               =     6,144
//   fbe : [NHID+1][B][H]   FiLM bias                                =    10,240
constexpr size_t OFS_DWT = 0;
constexpr size_t OFS_WT  = (size_t)NHID * B * H * H;
constexpr size_t OFS_DW0 = OFS_WT + (size_t)NHID * H * H;
constexpr size_t OFS_FBE = OFS_DW0 + (size_t)B * H * 3;

// ---------------------------------------------------------------------------
// fdlibm fp64 sine, error ~1e-16. Models numpy float32 sin as
// (float)sin((double)x). Used at LAYER 0 only (error gain 6.6e4 demands it).
// ---------------------------------------------------------------------------
__device__ __forceinline__ double sin_d(double x)
{
    const double INV_PIO2 = 6.36619772367581382433e-01;
    const double P1  = 1.57079632673412561417e+00;
    const double P1T = 6.07710050650619224932e-11;
    double fn = rint(x * INV_PIO2);
    int n = (int)fn;
    double r = fma(-fn, P1, x);
    r = fma(-fn, P1T, r);
    double z = r * r;
    double ps = fma(z, 1.58969099521155010221e-10, -2.50507602534068634195e-08);
    ps = fma(z, ps, 2.75573137070700676789e-06);
    ps = fma(z, ps, -1.98412698298579493134e-04);
    ps = fma(z, ps, 8.33333333332248946124e-03);
    ps = fma(z, ps, -1.66666666666666324348e-01);
    double s = fma(r * z, ps, r);
    double pc = fma(z, -1.13596475577881948265e-11, 2.08757232129817482790e-09);
    pc = fma(z, pc, -2.75573143513906633035e-07);
    pc = fma(z, pc, 2.48015872894767294178e-05);
    pc = fma(z, pc, -1.38888888888741095749e-03);
    pc = fma(z, pc, 4.16666666666666019037e-02);
    double c = fma(z * z, pc, fma(z, -0.5, 1.0));
    int k = n & 3;
    double v = (k & 1) ? c : s;
    return (k & 2) ? -v : v;
}

__device__ __forceinline__ float npsinf(float xf)
{
    return (float)sin_d((double)xf);
}

// ---------------------------------------------------------------------------
// Hybrid sine for hidden layers (r9-proven): fp64 Cody-Waite reduction +
// fp32 polynomials; ~1 ulp fp32 vs (float)sin(double).
// ---------------------------------------------------------------------------
__device__ __forceinline__ float sinh32(float xf)
{
    const double INV_PIO2 = 6.36619772367581382433e-01;
    const double P1  = 1.57079632673412561417e+00;
    const double P1T = 6.07710050650619224932e-11;
    double xd = (double)xf;
    double fn = rint(xd * INV_PIO2);
    int n = (int)fn;
    double rd = fma(-fn, P1, xd);
    rd = fma(-fn, P1T, rd);
    float r = (float)rd;
    float z = r * r;
    float ps = fmaf(z, 2.7183114939898219e-06f, -1.9839334836096632e-04f);
    ps = fmaf(z, ps, 8.3333293e-03f);
    ps = fmaf(z, ps, -1.6666667e-01f);
    float s = fmaf(r * z, ps, r);
    float pc = fmaf(z, 2.4390448796277409e-05f, -1.3888781739898680e-03f);
    pc = fmaf(z, pc, 4.1666667e-02f);
    float c = fmaf(z * z, pc, fmaf(z, -0.5f, 1.0f));
    int k = n & 3;
    float v = (k & 1) ? c : s;
    return (k & 2) ? -v : v;
}

// ---------------------------------------------------------------------------
// Materialize np's fp32 intermediates EXACTLY (r7/r8/r12 code, proven):
//   dW[l][b][o][i] = sum_r (U[l+1][o][r]*lat[b][r]) * V[l][i][r], stored [i][o]
// ---------------------------------------------------------------------------
__global__ void precomp_np(const float* __restrict__ lat, const float* __restrict__ U,
                           const float* __restrict__ V0,  const float* __restrict__ Vh,
                           const float* __restrict__ HB,
                           float* __restrict__ dwT, float* __restrict__ dw0,
                           float* __restrict__ fbe)
{
    int bi = blockIdx.x;
    int o  = threadIdx.x;
    if (bi < NHID * B) {
        int l = bi >> 3, b = bi & 7;
        const float* Uo = U + ((size_t)(l + 1) * H + o) * R;
        const float* lb = lat + b * R;
        float t[R];
        #pragma unroll
        for (int r = 0; r < R; ++r) t[r] = Uo[r] * lb[r];   // rounded fp32 mul
        const float* Vb = Vh + (size_t)l * H * R;
        float* dst = dwT + (size_t)(l * B + b) * H * H;     // [i][o]
        for (int i = 0; i < H; ++i) {
            const float* Vi = Vb + (size_t)i * R;
            float acc = 0.f;
            #pragma unroll
            for (int r = 0; r < R; ++r) acc = fmaf(t[r], Vi[r], acc);
            dst[(size_t)i * H + o] = acc;                   // coalesced over o
        }
    } else if (bi < NHID * B + B) {
        int b = bi - NHID * B;
        const float* Uo = U + (size_t)o * R;        // U[0][o][:]
        const float* lb = lat + b * R;
        float t[R];
        #pragma unroll
        for (int r = 0; r < R; ++r) t[r] = Uo[r] * lb[r];
        #pragma unroll
        for (int c = 0; c < C; ++c) {
            float acc = 0.f;
            #pragma unroll
            for (int r = 0; r < R; ++r) acc = fmaf(t[r], V0[c * R + r], acc);
            dw0[((size_t)b * H + o) * 3 + c] = acc;
        }
    } else {
        int b = bi - NHID * B - B;
        const float* lb = lat + b * R;
        for (int lidx = 0; lidx < NHID + 1; ++lidx) {
            const float* hb = HB + ((size_t)lidx * H + o) * R;
            float acc = 0.f;
            #pragma unroll
            for (int r = 0; r < R; ++r) acc = fmaf(lb[r], hb[r], acc);
            fbe[((size_t)lidx * B + b) * H + o] = acc;
        }
    }
}

// Pure bit-exact transpose: wT[l][i][o] = W_hid[l][o][i]
__global__ void transposeW(const float* __restrict__ Wh, float* __restrict__ wT)
{
    int li = blockIdx.x;           // l*H + i
    int o  = threadIdx.x;
    int l = li >> 8, i = li & 255;
    wT[(size_t)li * H + o] = Wh[((size_t)l * H + o) * H + i];
}

// ---------------------------------------------------------------------------
// np-replica forward, o4 x k16 tile (r12) with residency fixes:
//  - no cbuf (coords read direct from global; identical values) -> LDS 66560B
//  - k-loop split into 2 halves of 8 -> live av[] halved -> VGPR ~105
// Per-(n,o) arithmetic BIT-IDENTICAL to r12: lin and delta each = single
// fp32 acc, i ascending, fmaf over np-exact wT/dwT; ((lin+b)+delta)+fb,
// *30.0f, sin (L0 fp64, hidden hybrid). One wave = one 16-point group, so
// act LDS reads are wave-uniform broadcasts; weight loads are 1KB coalesced.
// ---------------------------------------------------------------------------
__launch_bounds__(BLOCK)
__global__ void siren_np(const float* __restrict__ coords,
                         const float* __restrict__ Wf, const float* __restrict__ bf,
                         const float* __restrict__ bh,
                         const float* __restrict__ Wl, const float* __restrict__ bl,
                         const float* __restrict__ wT, const float* __restrict__ dwT,
                         const float* __restrict__ dw0, const float* __restrict__ fbe,
                         float* __restrict__ out)
{
    __shared__ __align__(16) float abuf[PTS * PADA];   // 66,560 B -> 2 blocks/CU
    const int tid = threadIdx.x;
    const int og = tid & 63, pg = tid >> 6;
    const int o0 = og * 4, pbase = pg * 16;
    const int p0 = blockIdx.x * PTS;          // global point base
    const int b  = p0 >> 15;                  // N = 2^15; all 64 pts same batch

    // ---- layer 0 (same per-(n,o) arithmetic as rounds 6-12) ----
    {
        const float* fb0 = fbe + (size_t)(0 * B + b) * H;
        const float* cb  = coords + (size_t)(p0 + pbase) * 3;   // wave-uniform reads
        #pragma unroll
        for (int j = 0; j < 4; ++j) {
            const int o = o0 + j;
            const float wf0 = Wf[o * 3 + 0], wf1 = Wf[o * 3 + 1], wf2 = Wf[o * 3 + 2];
            const float* dwo = dw0 + ((size_t)b * H + o) * 3;
            const float dd0 = dwo[0], dd1 = dwo[1], dd2 = dwo[2];
            const float bo = bf[o], fo = fb0[o];
            for (int k = 0; k < 16; ++k) {
                const float x0 = cb[k * 3 + 0];
                const float x1 = cb[k * 3 + 1];
                const float x2 = cb[k * 3 + 2];
                float lin = 0.f;
                lin = fmaf(x0, wf0, lin);
                lin = fmaf(x1, wf1, lin);
                lin = fmaf(x2, wf2, lin);
                lin = lin + bo;
                float dl = 0.f;
                dl = fmaf(x0, dd0, dl);
                dl = fmaf(x1, dd1, dl);
                dl = fmaf(x2, dd2, dl);
                float z = (lin + dl) + fo;
                abuf[(pbase + k) * PADA + o] = npsinf(30.0f * z);
            }
        }
    }
    __syncthreads();

    // ---- hidden layers (single abuf; read-all / barrier / write-in-place) ----
    for (int l = 0; l < NHID; ++l) {
        const float4* Wt4 = (const float4*)(wT  + (size_t)l * H * H);
        const float4* Dt4 = (const float4*)(dwT + (size_t)(l * B + b) * H * H);

        float lacc[4][16], eacc[4][16];
        #pragma unroll
        for (int j = 0; j < 4; ++j)
            #pragma unroll
            for (int k = 0; k < 16; ++k) { lacc[j][k] = 0.f; eacc[j][k] = 0.f; }

        for (int i0 = 0; i0 < H; i0 += 4) {
            // weight rows: 8 fully-coalesced 1KB wave loads
            float4 w4[4], d4[4];
            #pragma unroll
            for (int ii = 0; ii < 4; ++ii) {
                w4[ii] = Wt4[(size_t)(i0 + ii) * 64 + og];
                d4[ii] = Dt4[(size_t)(i0 + ii) * 64 + og];
            }
            // two half-tiles of 8 points: halves live av registers (VGPR relief);
            // per-(n,o) accumulation order over i unchanged -> bit-exact.
            #pragma unroll
            for (int kh = 0; kh < 2; ++kh) {
                const int kb = kh * 8;
                float4 av[8];
                #pragma unroll
                for (int k = 0; k < 8; ++k)
                    av[k] = *(const float4*)(&abuf[(pbase + kb + k) * PADA + i0]);
                #pragma unroll
                for (int ii = 0; ii < 4; ++ii) {        // i ASCENDING (np sgemm)
                    const float wj[4] = {w4[ii].x, w4[ii].y, w4[ii].z, w4[ii].w};
                    const float dj[4] = {d4[ii].x, d4[ii].y, d4[ii].z, d4[ii].w};
                    #pragma unroll
                    for (int k = 0; k < 8; ++k) {
                        const float ai = (&av[k].x)[ii];
                        #pragma unroll
                        for (int j = 0; j < 4; ++j) {
                            lacc[j][kb + k] = fmaf(ai, wj[j], lacc[j][kb + k]);
                            eacc[j][kb + k] = fmaf(ai, dj[j], eacc[j][kb + k]);
                        }
                    }
                }
            }
        }
        __syncthreads();   // ALL reads of abuf complete before in-place writes
        {
            const float* be  = bh + (size_t)l * H;
            const float* fbl = fbe + (size_t)((l + 1) * B + b) * H;
            const float4 bo4 = *(const float4*)(be + o0);
            const float4 fo4 = *(const float4*)(fbl + o0);
            const float bo[4] = {bo4.x, bo4.y, bo4.z, bo4.w};
            const float fo[4] = {fo4.x, fo4.y, fo4.z, fo4.w};
            for (int k = 0; k < 16; ++k) {
                float4 rv;
                #pragma unroll
                for (int j = 0; j < 4; ++j) {
                    float z = ((lacc[j][k] + bo[j]) + eacc[j][k]) + fo[j];
                    (&rv.x)[j] = sinh32(30.0f * z);
                }
                *(float4*)(&abuf[(pbase + k) * PADA + o0]) = rv;
            }
        }
        __syncthreads();   // writes visible before next layer's reads
    }

    // ---- final projection (gain ~1) ----
    {
        const int n = tid >> 2, q = tid & 3;      // 4 threads cooperate per point
        const float* ar = abuf + n * PADA + q * 64;
        const float* wl = Wl + q * 64;
        float s = 0.f;
        #pragma unroll 16
        for (int t = 0; t < 64; ++t) s = fmaf(ar[t], wl[t], s);
        s += __shfl_xor(s, 1);
        s += __shfl_xor(s, 2);
        if (q == 0) out[p0 + n] = s + bl[0];
    }
}

// ---------------------------------------------------------------------------
extern "C" void kernel_launch(void* const* d_in, const int* in_sizes, int n_in,
                              void* d_out, int out_size, void* d_ws, size_t ws_size,
                              hipStream_t stream)
{
    const float* coords = (const float*)d_in[0];
    const float* lat    = (const float*)d_in[1];
    const float* Wf     = (const float*)d_in[2];
    const float* bf     = (const float*)d_in[3];
    const float* Wh     = (const float*)d_in[4];
    const float* bh     = (const float*)d_in[5];
    const float* Wl     = (const float*)d_in[6];
    const float* bl     = (const float*)d_in[7];
    const float* U      = (const float*)d_in[8];
    const float* V0     = (const float*)d_in[9];
    const float* Vh     = (const float*)d_in[10];
    const float* HB     = (const float*)d_in[11];

    float* ws  = (float*)d_ws;   // ~9.46 MB
    float* dwT = ws + OFS_DWT;
    float* wT  = ws + OFS_WT;
    float* dw0 = ws + OFS_DW0;
    float* fbe = ws + OFS_FBE;

    precomp_np<<<NHID * B + B + B, H, 0, stream>>>(lat, U, V0, Vh, HB, dwT, dw0, fbe);
    transposeW<<<NHID * H, H, 0, stream>>>(Wh, wT);
    siren_np<<<(B * N) / PTS, BLOCK, 0, stream>>>(coords, Wf, bf, bh, Wl, bl,
                                                  wT, dwT, dw0, fbe, (float*)d_out);
}

// Round 14
// 2672.137 us; speedup vs baseline: 1.3054x; 1.3054x over previous
//
#include <hip/hip_runtime.h>
#include <math.h>

// Problem constants (must match reference)
constexpr int B = 8, N = 32768, C = 3, H = 256, R = 64, NHID = 4;
constexpr int PTS   = 64;    // points per block
constexpr int BLOCK = 256;   // 4 waves; wave pg owns points pg*16..pg*16+15
constexpr int PADA  = 260;   // LDS act row stride

// Workspace (floats), total ~8.98 MB:
//   dwT01 : [2][B][H][H] np-exact dW for h0,h1, stored [i][o]   = 1,048,576 fl
//   wf23  : [2][B][H][H] FOLDED fl(W+dW) for h2,h3, [i][o]      = 1,048,576 fl
//   wT01  : [2][H][H]    W_hid[0..1] transposed [i][o] bit-exact=   131,072 fl
//   dw0   : [B][H][3]    layer-0 dW (np-exact)                  =     6,144 fl
//   fbe   : [NHID+1][B][H] FiLM bias                            =    10,240 fl
constexpr size_t OFS_DWT01 = 0;
constexpr size_t OFS_WF23  = (size_t)2 * B * H * H;
constexpr size_t OFS_WT01  = OFS_WF23 + (size_t)2 * B * H * H;
constexpr size_t OFS_DW0   = OFS_WT01 + (size_t)2 * H * H;
constexpr size_t OFS_FBE   = OFS_DW0 + (size_t)B * H * 3;

// ---------------------------------------------------------------------------
// fdlibm fp64 sine, error ~1e-16. Models numpy float32 sin as
// (float)sin((double)x). Used at LAYER 0 only (error gain 6.6e4 demands it).
// ---------------------------------------------------------------------------
__device__ __forceinline__ double sin_d(double x)
{
    const double INV_PIO2 = 6.36619772367581382433e-01;
    const double P1  = 1.57079632673412561417e+00;
    const double P1T = 6.07710050650619224932e-11;
    double fn = rint(x * INV_PIO2);
    int n = (int)fn;
    double r = fma(-fn, P1, x);
    r = fma(-fn, P1T, r);
    double z = r * r;
    double ps = fma(z, 1.58969099521155010221e-10, -2.50507602534068634195e-08);
    ps = fma(z, ps, 2.75573137070700676789e-06);
    ps = fma(z, ps, -1.98412698298579493134e-04);
    ps = fma(z, ps, 8.33333333332248946124e-03);
    ps = fma(z, ps, -1.66666666666666324348e-01);
    double s = fma(r * z, ps, r);
    double pc = fma(z, -1.13596475577881948265e-11, 2.08757232129817482790e-09);
    pc = fma(z, pc, -2.75573143513906633035e-07);
    pc = fma(z, pc, 2.48015872894767294178e-05);
    pc = fma(z, pc, -1.38888888888741095749e-03);
    pc = fma(z, pc, 4.16666666666666019037e-02);
    double c = fma(z * z, pc, fma(z, -0.5, 1.0));
    int k = n & 3;
    double v = (k & 1) ? c : s;
    return (k & 2) ? -v : v;
}

__device__ __forceinline__ float npsinf(float xf)
{
    return (float)sin_d((double)xf);
}

// ---------------------------------------------------------------------------
// Hybrid sine for hidden layers (r9-proven): fp64 Cody-Waite reduction +
// fp32 polynomials; ~1 ulp fp32 vs (float)sin(double).
// ---------------------------------------------------------------------------
__device__ __forceinline__ float sinh32(float xf)
{
    const double INV_PIO2 = 6.36619772367581382433e-01;
    const double P1  = 1.57079632673412561417e+00;
    const double P1T = 6.07710050650619224932e-11;
    double xd = (double)xf;
    double fn = rint(xd * INV_PIO2);
    int n = (int)fn;
    double rd = fma(-fn, P1, xd);
    rd = fma(-fn, P1T, rd);
    float r = (float)rd;
    float z = r * r;
    float ps = fmaf(z, 2.7183114939898219e-06f, -1.9839334836096632e-04f);
    ps = fmaf(z, ps, 8.3333293e-03f);
    ps = fmaf(z, ps, -1.6666667e-01f);
    float s = fmaf(r * z, ps, r);
    float pc = fmaf(z, 2.4390448796277409e-05f, -1.3888781739898680e-03f);
    pc = fmaf(z, pc, 4.1666667e-02f);
    float c = fmaf(z * z, pc, fmaf(z, -0.5f, 1.0f));
    int k = n & 3;
    float v = (k & 1) ? c : s;
    return (k & 2) ? -v : v;
}

// ---------------------------------------------------------------------------
// Precompute. dW computed np-exactly (t[r]=U*lat rounded; r-ascending fmaf).
// h0/h1: store dW exact [i][o]. h2/h3: store FOLDED fl(W[o][i] + dW) [i][o]
// (single rounded add; inject at out ~1e-3, gain-safe at these layers).
// ---------------------------------------------------------------------------
__global__ void precomp_np(const float* __restrict__ lat, const float* __restrict__ U,
                           const float* __restrict__ V0,  const float* __restrict__ Vh,
                           const float* __restrict__ Wh,  const float* __restrict__ HB,
                           float* __restrict__ dwT01, float* __restrict__ wf23,
                           float* __restrict__ dw0, float* __restrict__ fbe)
{
    int bi = blockIdx.x;
    int o  = threadIdx.x;
    if (bi < NHID * B) {
        int l = bi >> 3, b = bi & 7;
        const float* Uo = U + ((size_t)(l + 1) * H + o) * R;
        const float* lb = lat + b * R;
        float t[R];
        #pragma unroll
        for (int r = 0; r < R; ++r) t[r] = Uo[r] * lb[r];   // rounded fp32 mul
        const float* Vb = Vh + (size_t)l * H * R;
        if (l < 2) {
            float* dst = dwT01 + (size_t)(l * B + b) * H * H;   // exact dW [i][o]
            for (int i = 0; i < H; ++i) {
                const float* Vi = Vb + (size_t)i * R;
                float acc = 0.f;
                #pragma unroll
                for (int r = 0; r < R; ++r) acc = fmaf(t[r], Vi[r], acc);
                dst[(size_t)i * H + o] = acc;
            }
        } else {
            const float* Wl = Wh + (size_t)l * H * H;
            float* dst = wf23 + (size_t)((l - 2) * B + b) * H * H;  // folded [i][o]
            for (int i = 0; i < H; ++i) {
                const float* Vi = Vb + (size_t)i * R;
                float acc = 0.f;
                #pragma unroll
                for (int r = 0; r < R; ++r) acc = fmaf(t[r], Vi[r], acc);
                dst[(size_t)i * H + o] = Wl[(size_t)o * H + i] + acc;  // one rounded add
            }
        }
    } else if (bi < NHID * B + B) {
        int b = bi - NHID * B;
        const float* Uo = U + (size_t)o * R;        // U[0][o][:]
        const float* lb = lat + b * R;
        float t[R];
        #pragma unroll
        for (int r = 0; r < R; ++r) t[r] = Uo[r] * lb[r];
        #pragma unroll
        for (int c = 0; c < C; ++c) {
            float acc = 0.f;
            #pragma unroll
            for (int r = 0; r < R; ++r) acc = fmaf(t[r], V0[c * R + r], acc);
            dw0[((size_t)b * H + o) * 3 + c] = acc;
        }
    } else {
        int b = bi - NHID * B - B;
        const float* lb = lat + b * R;
        for (int lidx = 0; lidx < NHID + 1; ++lidx) {
            const float* hb = HB + ((size_t)lidx * H + o) * R;
            float acc = 0.f;
            #pragma unroll
            for (int r = 0; r < R; ++r) acc = fmaf(lb[r], hb[r], acc);
            fbe[((size_t)lidx * B + b) * H + o] = acc;
        }
    }
}

// Pure bit-exact transpose for h0,h1: wT01[l][i][o] = W_hid[l][o][i]
__global__ void transposeW(const float* __restrict__ Wh, float* __restrict__ wT01)
{
    int li = blockIdx.x;           // l*H + i, l in {0,1}
    int o  = threadIdx.x;
    int l = li >> 8, i = li & 255;
    wT01[(size_t)li * H + o] = Wh[((size_t)l * H + o) * H + i];
}

// ---------------------------------------------------------------------------
// np-replica forward, BARRIER-FREE: wave pg exclusively owns abuf rows
// pg*16..pg*16+15 in every phase (verified: L0, hidden av reads/writes,
// final n=tid>>2 all stay in-wave). Within-wave read->write ordering on the
// same rows is program-order guaranteed.
//  L0:     np-exact (fp64 sine)                                 [bit-exact]
//  h0,h1:  np-exact dual GEMM (lin over wT01, delta over dwT01), processed
//          as TWO 8-point passes (acc=64 VGPR). i-ascending single-acc
//          per (n,o) — identical FP sequence to r12/r13.        [bit-exact]
//  h2,h3:  FOLDED single GEMM over wf23; z=(linf+b)+fb.         [~1e-3 inject]
// ---------------------------------------------------------------------------
__launch_bounds__(BLOCK)
__global__ void siren_np(const float* __restrict__ coords,
                         const float* __restrict__ Wf, const float* __restrict__ bf,
                         const float* __restrict__ bh,
                         const float* __restrict__ Wl, const float* __restrict__ bl,
                         const float* __restrict__ wT01, const float* __restrict__ dwT01,
                         const float* __restrict__ wf23,
                         const float* __restrict__ dw0, const float* __restrict__ fbe,
                         float* __restrict__ out)
{
    __shared__ __align__(16) float abuf[PTS * PADA];   // 66,560 B -> 2 blocks/CU
    const int tid = threadIdx.x;
    const int og = tid & 63, pg = tid >> 6;
    const int o0 = og * 4, pbase = pg * 16;
    const int p0 = blockIdx.x * PTS;          // global point base
    const int b  = p0 >> 15;                  // N = 2^15; all 64 pts same batch

    // ---- layer 0 (np-exact, same FP sequence as rounds 6-13) ----
    {
        const float* fb0 = fbe + (size_t)(0 * B + b) * H;
        const float* cb  = coords + (size_t)(p0 + pbase) * 3;
        #pragma unroll
        for (int j = 0; j < 4; ++j) {
            const int o = o0 + j;
            const float wf0 = Wf[o * 3 + 0], wf1 = Wf[o * 3 + 1], wf2 = Wf[o * 3 + 2];
            const float* dwo = dw0 + ((size_t)b * H + o) * 3;
            const float dd0 = dwo[0], dd1 = dwo[1], dd2 = dwo[2];
            const float bo = bf[o], fo = fb0[o];
            for (int k = 0; k < 16; ++k) {
                const float x0 = cb[k * 3 + 0];
                const float x1 = cb[k * 3 + 1];
                const float x2 = cb[k * 3 + 2];
                float lin = 0.f;
                lin = fmaf(x0, wf0, lin);
                lin = fmaf(x1, wf1, lin);
                lin = fmaf(x2, wf2, lin);
                lin = lin + bo;
                float dl = 0.f;
                dl = fmaf(x0, dd0, dl);
                dl = fmaf(x1, dd1, dl);
                dl = fmaf(x2, dd2, dl);
                float z = (lin + dl) + fo;
                abuf[(pbase + k) * PADA + o] = npsinf(30.0f * z);
            }
        }
    }
    // no barrier: h0 reads only this wave's rows

    // ---- h0, h1: np-exact dual GEMM, two 8-point passes each ----
    for (int l = 0; l < 2; ++l) {
        const float4* Wt4 = (const float4*)(wT01  + (size_t)l * H * H);
        const float4* Dt4 = (const float4*)(dwT01 + (size_t)(l * B + b) * H * H);
        const float* be  = bh + (size_t)l * H;
        const float* fbl = fbe + (size_t)((l + 1) * B + b) * H;
        const float4 bo4 = *(const float4*)(be + o0);
        const float4 fo4 = *(const float4*)(fbl + o0);
        const float bo[4] = {bo4.x, bo4.y, bo4.z, bo4.w};
        const float fo[4] = {fo4.x, fo4.y, fo4.z, fo4.w};

        for (int kh = 0; kh < 2; ++kh) {
            const int kb = pbase + kh * 8;
            float lacc[4][8], eacc[4][8];
            #pragma unroll
            for (int j = 0; j < 4; ++j)
                #pragma unroll
                for (int k = 0; k < 8; ++k) { lacc[j][k] = 0.f; eacc[j][k] = 0.f; }

            for (int i0 = 0; i0 < H; i0 += 4) {
                float4 w4[4], d4[4];
                #pragma unroll
                for (int ii = 0; ii < 4; ++ii) {
                    w4[ii] = Wt4[(size_t)(i0 + ii) * 64 + og];
                    d4[ii] = Dt4[(size_t)(i0 + ii) * 64 + og];
                }
                #pragma unroll
                for (int k = 0; k < 8; ++k) {
                    const float4 av = *(const float4*)(&abuf[(kb + k) * PADA + i0]);
                    #pragma unroll
                    for (int ii = 0; ii < 4; ++ii) {   // i ASCENDING per (n,o)
                        const float ai = (&av.x)[ii];
                        #pragma unroll
                        for (int j = 0; j < 4; ++j) {
                            lacc[j][k] = fmaf(ai, (&w4[ii].x)[j], lacc[j][k]);
                            eacc[j][k] = fmaf(ai, (&d4[ii].x)[j], eacc[j][k]);
                        }
                    }
                }
            }
            // epilogue for these 8 rows (reads of them are complete; in-wave order)
            #pragma unroll
            for (int k = 0; k < 8; ++k) {
                float4 rv;
                #pragma unroll
                for (int j = 0; j < 4; ++j) {
                    float z = ((lacc[j][k] + bo[j]) + eacc[j][k]) + fo[j];
                    (&rv.x)[j] = sinh32(30.0f * z);
                }
                *(float4*)(&abuf[(kb + k) * PADA + o0]) = rv;
            }
        }
    }

    // ---- h2, h3: folded single GEMM, 16 points, acc = 64 VGPR ----
    for (int l = 0; l < 2; ++l) {
        const float4* Ft4 = (const float4*)(wf23 + (size_t)(l * B + b) * H * H);
        const float* be  = bh + (size_t)(l + 2) * H;
        const float* fbl = fbe + (size_t)((l + 3) * B + b) * H;
        const float4 bo4 = *(const float4*)(be + o0);
        const float4 fo4 = *(const float4*)(fbl + o0);
        const float bo[4] = {bo4.x, bo4.y, bo4.z, bo4.w};
        const float fo[4] = {fo4.x, fo4.y, fo4.z, fo4.w};

        float lacc[4][16];
        #pragma unroll
        for (int j = 0; j < 4; ++j)
            #pragma unroll
            for (int k = 0; k < 16; ++k) lacc[j][k] = 0.f;

        for (int i0 = 0; i0 < H; i0 += 4) {
            float4 w4[4];
            #pragma unroll
            for (int ii = 0; ii < 4; ++ii)
                w4[ii] = Ft4[(size_t)(i0 + ii) * 64 + og];
            #pragma unroll
            for (int k = 0; k < 16; ++k) {
                const float4 av = *(const float4*)(&abuf[(pbase + k) * PADA + i0]);
                #pragma unroll
                for (int ii = 0; ii < 4; ++ii) {       // i ASCENDING per (n,o)
                    const float ai = (&av.x)[ii];
                    #pragma unroll
                    for (int j = 0; j < 4; ++j)
                        lacc[j][k] = fmaf(ai, (&w4[ii].x)[j], lacc[j][k]);
                }
            }
        }
        #pragma unroll
        for (int k = 0; k < 16; ++k) {
            float4 rv;
            #pragma unroll
            for (int j = 0; j < 4; ++j) {
                float z = (lacc[j][k] + bo[j]) + fo[j];   // folded: linf ~ lin+delta
                (&rv.x)[j] = sinh32(30.0f * z);
            }
            *(float4*)(&abuf[(pbase + k) * PADA + o0]) = rv;
        }
    }

    // ---- final projection (own rows: n = tid>>2 in [pbase, pbase+16)) ----
    {
        const int n = tid >> 2, q = tid & 3;
        const float* ar = abuf + n * PADA + q * 64;
        const float* wl = Wl + q * 64;
        float s = 0.f;
        #pragma unroll 16
        for (int t = 0; t < 64; ++t) s = fmaf(ar[t], wl[t], s);
        s += __shfl_xor(s, 1);
        s += __shfl_xor(s, 2);
        if (q == 0) out[p0 + n] = s + bl[0];
    }
}

// ---------------------------------------------------------------------------
extern "C" void kernel_launch(void* const* d_in, const int* in_sizes, int n_in,
                              void* d_out, int out_size, void* d_ws, size_t ws_size,
                              hipStream_t stream)
{
    const float* coords = (const float*)d_in[0];
    const float* lat    = (const float*)d_in[1];
    const float* Wf     = (const float*)d_in[2];
    const float* bf     = (const float*)d_in[3];
    const float* Wh     = (const float*)d_in[4];
    const float* bh     = (const float*)d_in[5];
    const float* Wl     = (const float*)d_in[6];
    const float* bl     = (const float*)d_in[7];
    const float* U      = (const float*)d_in[8];
    const float* V0     = (const float*)d_in[9];
    const float* Vh     = (const float*)d_in[10];
    const float* HB     = (const float*)d_in[11];

    float* ws    = (float*)d_ws;   // ~8.98 MB
    float* dwT01 = ws + OFS_DWT01;
    float* wf23  = ws + OFS_WF23;
    float* wT01  = ws + OFS_WT01;
    float* dw0   = ws + OFS_DW0;
    float* fbe   = ws + OFS_FBE;

    precomp_np<<<NHID * B + B + B, H, 0, stream>>>(lat, U, V0, Vh, Wh, HB,
                                                   dwT01, wf23, dw0, fbe);
    transposeW<<<2 * H, H, 0, stream>>>(Wh, wT01);
    siren_np<<<(B * N) / PTS, BLOCK, 0, stream>>>(coords, Wf, bf, bh, Wl, bl,
                                                  wT01, dwT01, wf23, dw0, fbe,
                                                  (float*)d_out);
}

// Round 15
// 2249.352 us; speedup vs baseline: 1.5507x; 1.1880x over previous
//
#include <hip/hip_runtime.h>
#include <math.h>

// Problem constants (must match reference)
constexpr int B = 8, N = 32768, C = 3, H = 256, R = 64, NHID = 4;
constexpr int PTS   = 64;    // points per block
constexpr int BLOCK = 256;   // 4 waves; wave pg owns points pg*16..pg*16+15
constexpr int PADA  = 260;   // LDS act row stride

// Workspace (floats), total ~8.7 MB:
//   dwT0  : [B][H][H]    np-exact dW for h0, stored [i][o]      =   524,288 fl
//   wf123 : [3][B][H][H] FOLDED fl(W+dW) for h1..h3, [i][o]     = 1,572,864 fl
//   wT0   : [H][H]       W_hid[0] transposed [i][o] bit-exact   =    65,536 fl
//   dw0   : [B][H][3]    layer-0 dW (np-exact)                  =     6,144 fl
//   fbe   : [NHID+1][B][H] FiLM bias                            =    10,240 fl
constexpr size_t OFS_DWT0  = 0;
constexpr size_t OFS_WF123 = (size_t)B * H * H;
constexpr size_t OFS_WT0   = OFS_WF123 + (size_t)3 * B * H * H;
constexpr size_t OFS_DW0   = OFS_WT0 + (size_t)H * H;
constexpr size_t OFS_FBE   = OFS_DW0 + (size_t)B * H * 3;

// ---------------------------------------------------------------------------
// fdlibm fp64 sine, error ~1e-16. Models numpy float32 sin as
// (float)sin((double)x). Used at LAYER 0 only (error gain ~1e6 demands it).
// ---------------------------------------------------------------------------
__device__ __forceinline__ double sin_d(double x)
{
    const double INV_PIO2 = 6.36619772367581382433e-01;
    const double P1  = 1.57079632673412561417e+00;
    const double P1T = 6.07710050650619224932e-11;
    double fn = rint(x * INV_PIO2);
    int n = (int)fn;
    double r = fma(-fn, P1, x);
    r = fma(-fn, P1T, r);
    double z = r * r;
    double ps = fma(z, 1.58969099521155010221e-10, -2.50507602534068634195e-08);
    ps = fma(z, ps, 2.75573137070700676789e-06);
    ps = fma(z, ps, -1.98412698298579493134e-04);
    ps = fma(z, ps, 8.33333333332248946124e-03);
    ps = fma(z, ps, -1.66666666666666324348e-01);
    double s = fma(r * z, ps, r);
    double pc = fma(z, -1.13596475577881948265e-11, 2.08757232129817482790e-09);
    pc = fma(z, pc, -2.75573143513906633035e-07);
    pc = fma(z, pc, 2.48015872894767294178e-05);
    pc = fma(z, pc, -1.38888888888741095749e-03);
    pc = fma(z, pc, 4.16666666666666019037e-02);
    double c = fma(z * z, pc, fma(z, -0.5, 1.0));
    int k = n & 3;
    double v = (k & 1) ? c : s;
    return (k & 2) ? -v : v;
}

__device__ __forceinline__ float npsinf(float xf)
{
    return (float)sin_d((double)xf);
}

// ---------------------------------------------------------------------------
// Hybrid sine for hidden layers (r9-proven): fp64 Cody-Waite reduction +
// fp32 polynomials; ~1 ulp fp32 vs (float)sin(double).
// ---------------------------------------------------------------------------
__device__ __forceinline__ float sinh32(float xf)
{
    const double INV_PIO2 = 6.36619772367581382433e-01;
    const double P1  = 1.57079632673412561417e+00;
    const double P1T = 6.07710050650619224932e-11;
    double xd = (double)xf;
    double fn = rint(xd * INV_PIO2);
    int n = (int)fn;
    double rd = fma(-fn, P1, xd);
    rd = fma(-fn, P1T, rd);
    float r = (float)rd;
    float z = r * r;
    float ps = fmaf(z, 2.7183114939898219e-06f, -1.9839334836096632e-04f);
    ps = fmaf(z, ps, 8.3333293e-03f);
    ps = fmaf(z, ps, -1.6666667e-01f);
    float s = fmaf(r * z, ps, r);
    float pc = fmaf(z, 2.4390448796277409e-05f, -1.3888781739898680e-03f);
    pc = fmaf(z, pc, 4.1666667e-02f);
    float c = fmaf(z * z, pc, fmaf(z, -0.5f, 1.0f));
    int k = n & 3;
    float v = (k & 1) ? c : s;
    return (k & 2) ? -v : v;
}

// ---------------------------------------------------------------------------
// Precompute. dW computed np-exactly (t[r]=U*lat rounded; r-ascending fmaf).
// h0: store dW exact [i][o]. h1/h2/h3: store FOLDED fl(W[o][i]+dW) [i][o]
// (single rounded add; injects ~5e-7 at z3/z4/z5, gains 5e3/290/17 -> safe).
// ---------------------------------------------------------------------------
__global__ void precomp_np(const float* __restrict__ lat, const float* __restrict__ U,
                           const float* __restrict__ V0,  const float* __restrict__ Vh,
                           const float* __restrict__ Wh,  const float* __restrict__ HB,
                           float* __restrict__ dwT0, float* __restrict__ wf123,
                           float* __restrict__ dw0, float* __restrict__ fbe)
{
    int bi = blockIdx.x;
    int o  = threadIdx.x;
    if (bi < NHID * B) {
        int l = bi >> 3, b = bi & 7;
        const float* Uo = U + ((size_t)(l + 1) * H + o) * R;
        const float* lb = lat + b * R;
        float t[R];
        #pragma unroll
        for (int r = 0; r < R; ++r) t[r] = Uo[r] * lb[r];   // rounded fp32 mul
        const float* Vb = Vh + (size_t)l * H * R;
        if (l == 0) {
            float* dst = dwT0 + (size_t)b * H * H;          // exact dW [i][o]
            for (int i = 0; i < H; ++i) {
                const float* Vi = Vb + (size_t)i * R;
                float acc = 0.f;
                #pragma unroll
                for (int r = 0; r < R; ++r) acc = fmaf(t[r], Vi[r], acc);
                dst[(size_t)i * H + o] = acc;
            }
        } else {
            const float* Wl = Wh + (size_t)l * H * H;
            float* dst = wf123 + (size_t)((l - 1) * B + b) * H * H;  // folded [i][o]
            for (int i = 0; i < H; ++i) {
                const float* Vi = Vb + (size_t)i * R;
                float acc = 0.f;
                #pragma unroll
                for (int r = 0; r < R; ++r) acc = fmaf(t[r], Vi[r], acc);
                dst[(size_t)i * H + o] = Wl[(size_t)o * H + i] + acc;  // one rounded add
            }
        }
    } else if (bi < NHID * B + B) {
        int b = bi - NHID * B;
        const float* Uo = U + (size_t)o * R;        // U[0][o][:]
        const float* lb = lat + b * R;
        float t[R];
        #pragma unroll
        for (int r = 0; r < R; ++r) t[r] = Uo[r] * lb[r];
        #pragma unroll
        for (int c = 0; c < C; ++c) {
            float acc = 0.f;
            #pragma unroll
            for (int r = 0; r < R; ++r) acc = fmaf(t[r], V0[c * R + r], acc);
            dw0[((size_t)b * H + o) * 3 + c] = acc;
        }
    } else {
        int b = bi - NHID * B - B;
        const float* lb = lat + b * R;
        for (int lidx = 0; lidx < NHID + 1; ++lidx) {
            const float* hb = HB + ((size_t)lidx * H + o) * R;
            float acc = 0.f;
            #pragma unroll
            for (int r = 0; r < R; ++r) acc = fmaf(lb[r], hb[r], acc);
            fbe[((size_t)lidx * B + b) * H + o] = acc;
        }
    }
}

// Pure bit-exact transpose for h0: wT0[i][o] = W_hid[0][o][i]
__global__ void transposeW(const float* __restrict__ Wh, float* __restrict__ wT0)
{
    int i = blockIdx.x;
    int o = threadIdx.x;
    wT0[(size_t)i * H + o] = Wh[(size_t)o * H + i];
}

// ---------------------------------------------------------------------------
// np-replica forward, BARRIER-FREE (wave pg exclusively owns abuf rows
// pg*16..pg*16+15 in every phase; in-wave program order suffices).
//  L0:       np-exact (fp64 sine)                               [bit-exact]
//  h0:       np-exact dual GEMM (lin over wT0, delta over dwT0),
//            two 8-point passes, i-ascending single acc.        [bit-exact]
//  h1,h2,h3: FOLDED single GEMM over wf123; z=(linf+b)+fb.      [safe inject]
// ---------------------------------------------------------------------------
__launch_bounds__(BLOCK)
__global__ void siren_np(const float* __restrict__ coords,
                         const float* __restrict__ Wf, const float* __restrict__ bf,
                         const float* __restrict__ bh,
                         const float* __restrict__ Wl, const float* __restrict__ bl,
                         const float* __restrict__ wT0, const float* __restrict__ dwT0,
                         const float* __restrict__ wf123,
                         const float* __restrict__ dw0, const float* __restrict__ fbe,
                         float* __restrict__ out)
{
    __shared__ __align__(16) float abuf[PTS * PADA];   // 66,560 B -> 2 blocks/CU
    const int tid = threadIdx.x;
    const int og = tid & 63, pg = tid >> 6;
    const int o0 = og * 4, pbase = pg * 16;
    const int p0 = blockIdx.x * PTS;          // global point base
    const int b  = p0 >> 15;                  // N = 2^15; all 64 pts same batch

    // ---- layer 0 (np-exact, same FP sequence as rounds 6-14) ----
    {
        const float* fb0 = fbe + (size_t)(0 * B + b) * H;
        const float* cb  = coords + (size_t)(p0 + pbase) * 3;
        #pragma unroll
        for (int j = 0; j < 4; ++j) {
            const int o = o0 + j;
            const float wf0 = Wf[o * 3 + 0], wf1 = Wf[o * 3 + 1], wf2 = Wf[o * 3 + 2];
            const float* dwo = dw0 + ((size_t)b * H + o) * 3;
            const float dd0 = dwo[0], dd1 = dwo[1], dd2 = dwo[2];
            const float bo = bf[o], fo = fb0[o];
            for (int k = 0; k < 16; ++k) {
                const float x0 = cb[k * 3 + 0];
                const float x1 = cb[k * 3 + 1];
                const float x2 = cb[k * 3 + 2];
                float lin = 0.f;
                lin = fmaf(x0, wf0, lin);
                lin = fmaf(x1, wf1, lin);
                lin = fmaf(x2, wf2, lin);
                lin = lin + bo;
                float dl = 0.f;
                dl = fmaf(x0, dd0, dl);
                dl = fmaf(x1, dd1, dl);
                dl = fmaf(x2, dd2, dl);
                float z = (lin + dl) + fo;
                abuf[(pbase + k) * PADA + o] = npsinf(30.0f * z);
            }
        }
    }
    // no barrier: h0 reads only this wave's rows

    // ---- h0: np-exact dual GEMM, two 8-point passes ----
    {
        const float4* Wt4 = (const float4*)wT0;
        const float4* Dt4 = (const float4*)(dwT0 + (size_t)b * H * H);
        const float* be  = bh;                               // bh[0][:]
        const float* fbl = fbe + (size_t)(1 * B + b) * H;
        const float4 bo4 = *(const float4*)(be + o0);
        const float4 fo4 = *(const float4*)(fbl + o0);
        const float bo[4] = {bo4.x, bo4.y, bo4.z, bo4.w};
        const float fo[4] = {fo4.x, fo4.y, fo4.z, fo4.w};

        for (int kh = 0; kh < 2; ++kh) {
            const int kb = pbase + kh * 8;
            float lacc[4][8], eacc[4][8];
            #pragma unroll
            for (int j = 0; j < 4; ++j)
                #pragma unroll
                for (int k = 0; k < 8; ++k) { lacc[j][k] = 0.f; eacc[j][k] = 0.f; }

            for (int i0 = 0; i0 < H; i0 += 4) {
                float4 w4[4], d4[4];
                #pragma unroll
                for (int ii = 0; ii < 4; ++ii) {
                    w4[ii] = Wt4[(size_t)(i0 + ii) * 64 + og];
                    d4[ii] = Dt4[(size_t)(i0 + ii) * 64 + og];
                }
                #pragma unroll
                for (int k = 0; k < 8; ++k) {
                    const float4 av = *(const float4*)(&abuf[(kb + k) * PADA + i0]);
                    #pragma unroll
                    for (int ii = 0; ii < 4; ++ii) {   // i ASCENDING per (n,o)
                        const float ai = (&av.x)[ii];
                        #pragma unroll
                        for (int j = 0; j < 4; ++j) {
                            lacc[j][k] = fmaf(ai, (&w4[ii].x)[j], lacc[j][k]);
                            eacc[j][k] = fmaf(ai, (&d4[ii].x)[j], eacc[j][k]);
                        }
                    }
                }
            }
            #pragma unroll
            for (int k = 0; k < 8; ++k) {
                float4 rv;
                #pragma unroll
                for (int j = 0; j < 4; ++j) {
                    float z = ((lacc[j][k] + bo[j]) + eacc[j][k]) + fo[j];
                    (&rv.x)[j] = sinh32(30.0f * z);
                }
                *(float4*)(&abuf[(kb + k) * PADA + o0]) = rv;
            }
        }
    }

    // ---- h1, h2, h3: folded single GEMM, 16 points each ----
    for (int lf = 0; lf < 3; ++lf) {
        const float4* Ft4 = (const float4*)(wf123 + (size_t)(lf * B + b) * H * H);
        const float* be  = bh + (size_t)(lf + 1) * H;
        const float* fbl = fbe + (size_t)((lf + 2) * B + b) * H;
        const float4 bo4 = *(const float4*)(be + o0);
        const float4 fo4 = *(const float4*)(fbl + o0);
        const float bo[4] = {bo4.x, bo4.y, bo4.z, bo4.w};
        const float fo[4] = {fo4.x, fo4.y, fo4.z, fo4.w};

        float lacc[4][16];
        #pragma unroll
        for (int j = 0; j < 4; ++j)
            #pragma unroll
            for (int k = 0; k < 16; ++k) lacc[j][k] = 0.f;

        for (int i0 = 0; i0 < H; i0 += 4) {
            float4 w4[4];
            #pragma unroll
            for (int ii = 0; ii < 4; ++ii)
                w4[ii] = Ft4[(size_t)(i0 + ii) * 64 + og];
            #pragma unroll
            for (int k = 0; k < 16; ++k) {
                const float4 av = *(const float4*)(&abuf[(pbase + k) * PADA + i0]);
                #pragma unroll
                for (int ii = 0; ii < 4; ++ii) {       // i ASCENDING per (n,o)
                    const float ai = (&av.x)[ii];
                    #pragma unroll
                    for (int j = 0; j < 4; ++j)
                        lacc[j][k] = fmaf(ai, (&w4[ii].x)[j], lacc[j][k]);
                }
            }
        }
        #pragma unroll
        for (int k = 0; k < 16; ++k) {
            float4 rv;
            #pragma unroll
            for (int j = 0; j < 4; ++j) {
                float z = (lacc[j][k] + bo[j]) + fo[j];   // folded: linf ~ lin+delta
                (&rv.x)[j] = sinh32(30.0f * z);
            }
            *(float4*)(&abuf[(pbase + k) * PADA + o0]) = rv;
        }
    }

    // ---- final projection (own rows: n = tid>>2 in [pbase, pbase+16)) ----
    {
        const int n = tid >> 2, q = tid & 3;
        const float* ar = abuf + n * PADA + q * 64;
        const float* wl = Wl + q * 64;
        float s = 0.f;
        #pragma unroll 16
        for (int t = 0; t < 64; ++t) s = fmaf(ar[t], wl[t], s);
        s += __shfl_xor(s, 1);
        s += __shfl_xor(s, 2);
        if (q == 0) out[p0 + n] = s + bl[0];
    }
}

// ---------------------------------------------------------------------------
extern "C" void kernel_launch(void* const* d_in, const int* in_sizes, int n_in,
                              void* d_out, int out_size, void* d_ws, size_t ws_size,
                              hipStream_t stream)
{
    const float* coords = (const float*)d_in[0];
    const float* lat    = (const float*)d_in[1];
    const float* Wf     = (const float*)d_in[2];
    const float* bf     = (const float*)d_in[3];
    const float* Wh     = (const float*)d_in[4];
    const float* bh     = (const float*)d_in[5];
    const float* Wl     = (const float*)d_in[6];
    const float* bl     = (const float*)d_in[7];
    const float* U      = (const float*)d_in[8];
    const float* V0     = (const float*)d_in[9];
    const float* Vh     = (const float*)d_in[10];
    const float* HB     = (const float*)d_in[11];

    float* ws    = (float*)d_ws;   // ~8.7 MB
    float* dwT0  = ws + OFS_DWT0;
    float* wf123 = ws + OFS_WF123;
    float* wT0   = ws + OFS_WT0;
    float* dw0   = ws + OFS_DW0;
    float* fbe   = ws + OFS_FBE;

    precomp_np<<<NHID * B + B + B, H, 0, stream>>>(lat, U, V0, Vh, Wh, HB,
                                                   dwT0, wf123, dw0, fbe);
    transposeW<<<H, H, 0, stream>>>(Wh, wT0);
    siren_np<<<(B * N) / PTS, BLOCK, 0, stream>>>(coords, Wf, bf, bh, Wl, bl,
                                                  wT0, dwT0, wf123, dw0, fbe,
                                                  (float*)d_out);
}

// Round 18
// 2248.108 us; speedup vs baseline: 1.5516x; 1.0006x over previous
//
#include <hip/hip_runtime.h>
#include <math.h>

// Problem constants (must match reference)
constexpr int B = 8, N = 32768, C = 3, H = 256, R = 64, NHID = 4;
constexpr int PTS   = 64;    // points per block
constexpr int BLOCK = 256;   // 4 waves; wave pg owns points pg*16..pg*16+15
constexpr int PADA  = 260;   // LDS act row stride

// Workspace (floats), total ~8.7 MB:
//   dwT0  : [B][H][H]    np-exact dW for h0, stored [i][o]      =   524,288 fl
//   wf123 : [3][B][H][H] FOLDED fl(W+dW) for h1..h3, [i][o]     = 1,572,864 fl
//   wT0   : [H][H]       W_hid[0] transposed [i][o] bit-exact   =    65,536 fl
//   dw0   : [B][H][3]    layer-0 dW (np-exact)                  =     6,144 fl
//   fbe   : [NHID+1][B][H] FiLM bias                            =    10,240 fl
constexpr size_t OFS_DWT0  = 0;
constexpr size_t OFS_WF123 = (size_t)B * H * H;
constexpr size_t OFS_WT0   = OFS_WF123 + (size_t)3 * B * H * H;
constexpr size_t OFS_DW0   = OFS_WT0 + (size_t)H * H;
constexpr size_t OFS_FBE   = OFS_DW0 + (size_t)B * H * 3;

// ---------------------------------------------------------------------------
// fdlibm-style fp64 sine, error ~1e-16. Models numpy's float32 sin as
// (float)sin((double)x). Used at LAYER 0 only (error gain ~1e6 demands it).
// ---------------------------------------------------------------------------
__device__ __forceinline__ double sin_d(double x)
{
    const double INV_PIO2 = 6.36619772367581382433e-01;
    const double P1  = 1.57079632673412561417e+00;
    const double P1T = 6.07710050650619224932e-11;
    double fn = rint(x * INV_PIO2);
    int n = (int)fn;
    double r = fma(-fn, P1, x);
    r = fma(-fn, P1T, r);
    double z = r * r;
    double ps = fma(z, 1.58969099521155010221e-10, -2.50507602534068634195e-08);
    ps = fma(z, ps, 2.75573137070700676789e-06);
    ps = fma(z, ps, -1.98412698298579493134e-04);
    ps = fma(z, ps, 8.33333333332248946124e-03);
    ps = fma(z, ps, -1.66666666666666324348e-01);
    double s = fma(r * z, ps, r);
    double pc = fma(z, -1.13596475577881948265e-11, 2.08757232129817482790e-09);
    pc = fma(z, pc, -2.75573143513906633035e-07);
    pc = fma(z, pc, 2.48015872894767294178e-05);
    pc = fma(z, pc, -1.38888888888741095749e-03);
    pc = fma(z, pc, 4.16666666666666019037e-02);
    double c = fma(z * z, pc, fma(z, -0.5, 1.0));
    int k = n & 3;
    double v = (k & 1) ? c : s;
    return (k & 2) ? -v : v;
}

__device__ __forceinline__ float npsinf(float xf)
{
    return (float)sin_d((double)xf);
}

// ---------------------------------------------------------------------------
// Hybrid sine for hidden layers (r9-proven): fp64 Cody-Waite reduction +
// fp32 polynomials; ~1 ulp fp32 vs (float)sin(double).
// ---------------------------------------------------------------------------
__device__ __forceinline__ float sinh32(float xf)
{
    const double INV_PIO2 = 6.36619772367581382433e-01;
    const double P1  = 1.57079632673412561417e+00;
    const double P1T = 6.07710050650619224932e-11;
    double xd = (double)xf;
    double fn = rint(xd * INV_PIO2);
    int n = (int)fn;
    double rd = fma(-fn, P1, xd);
    rd = fma(-fn, P1T, rd);
    float r = (float)rd;
    float z = r * r;
    float ps = fmaf(z, 2.7183114939898219e-06f, -1.9839334836096632e-04f);
    ps = fmaf(z, ps, 8.3333293e-03f);
    ps = fmaf(z, ps, -1.6666667e-01f);
    float s = fmaf(r * z, ps, r);
    float pc = fmaf(z, 2.4390448796277409e-05f, -1.3888781739898680e-03f);
    pc = fmaf(z, pc, 4.1666667e-02f);
    float c = fmaf(z * z, pc, fmaf(z, -0.5f, 1.0f));
    int k = n & 3;
    float v = (k & 1) ? c : s;
    return (k & 2) ? -v : v;
}

// ---------------------------------------------------------------------------
// Precompute. dW computed np-exactly (t[r]=U*lat rounded; r-ascending fmaf).
// h0: store dW exact [i][o]. h1/h2/h3: store FOLDED fl(W[o][i]+dW) [i][o]
// (single rounded add; injects ~5e-7 at z3/z4/z5, gains 5e3/290/17 -> safe).
// ---------------------------------------------------------------------------
__global__ void precomp_np(const float* __restrict__ lat, const float* __restrict__ U,
                           const float* __restrict__ V0,  const float* __restrict__ Vh,
                           const float* __restrict__ Wh,  const float* __restrict__ HB,
                           float* __restrict__ dwT0, float* __restrict__ wf123,
                           float* __restrict__ dw0, float* __restrict__ fbe)
{
    int bi = blockIdx.x;
    int o  = threadIdx.x;
    if (bi < NHID * B) {
        int l = bi >> 3, b = bi & 7;
        const float* Uo = U + ((size_t)(l + 1) * H + o) * R;
        const float* lb = lat + b * R;
        float t[R];
        #pragma unroll
        for (int r = 0; r < R; ++r) t[r] = Uo[r] * lb[r];   // rounded fp32 mul
        const float* Vb = Vh + (size_t)l * H * R;
        if (l == 0) {
            float* dst = dwT0 + (size_t)b * H * H;          // exact dW [i][o]
            for (int i = 0; i < H; ++i) {
                const float* Vi = Vb + (size_t)i * R;
                float acc = 0.f;
                #pragma unroll
                for (int r = 0; r < R; ++r) acc = fmaf(t[r], Vi[r], acc);
                dst[(size_t)i * H + o] = acc;
            }
        } else {
            const float* Wl = Wh + (size_t)l * H * H;
            float* dst = wf123 + (size_t)((l - 1) * B + b) * H * H;  // folded [i][o]
            for (int i = 0; i < H; ++i) {
                const float* Vi = Vb + (size_t)i * R;
                float acc = 0.f;
                #pragma unroll
                for (int r = 0; r < R; ++r) acc = fmaf(t[r], Vi[r], acc);
                dst[(size_t)i * H + o] = Wl[(size_t)o * H + i] + acc;  // one rounded add
            }
        }
    } else if (bi < NHID * B + B) {
        int b = bi - NHID * B;
        const float* Uo = U + (size_t)o * R;        // U[0][o][:]
        const float* lb = lat + b * R;
        float t[R];
        #pragma unroll
        for (int r = 0; r < R; ++r) t[r] = Uo[r] * lb[r];
        #pragma unroll
        for (int c = 0; c < C; ++c) {
            float acc = 0.f;
            #pragma unroll
            for (int r = 0; r < R; ++r) acc = fmaf(t[r], V0[c * R + r], acc);
            dw0[((size_t)b * H + o) * 3 + c] = acc;
        }
    } else {
        int b = bi - NHID * B - B;
        const float* lb = lat + b * R;
        for (int lidx = 0; lidx < NHID + 1; ++lidx) {
            const float* hb = HB + ((size_t)lidx * H + o) * R;
            float acc = 0.f;
            #pragma unroll
            for (int r = 0; r < R; ++r) acc = fmaf(lb[r], hb[r], acc);
            fbe[((size_t)lidx * B + b) * H + o] = acc;
        }
    }
}

// Pure bit-exact transpose for h0: wT0[i][o] = W_hid[0][o][i]
__global__ void transposeW(const float* __restrict__ Wh, float* __restrict__ wT0)
{
    int i = blockIdx.x;
    int o = threadIdx.x;
    wT0[(size_t)i * H + o] = Wh[(size_t)o * H + i];
}

// ---------------------------------------------------------------------------
// np-replica forward, BARRIER-FREE (wave pg exclusively owns abuf rows
// pg*16..pg*16+15 in every phase; in-wave program order suffices).
//  L0:       np-exact (fp64 sine)                               [bit-exact]
//  h0:       np-exact dual GEMM (lin over wT0, delta over dwT0),
//            two 8-point passes, i-ascending single acc.        [bit-exact]
//  h1,h2,h3: FOLDED single GEMM over wf123; z=(linf+b)+fb.      [safe inject]
// ---------------------------------------------------------------------------
__launch_bounds__(BLOCK)
__global__ void siren_np(const float* __restrict__ coords,
                         const float* __restrict__ Wf, const float* __restrict__ bf,
                         const float* __restrict__ bh,
                         const float* __restrict__ Wl, const float* __restrict__ bl,
                         const float* __restrict__ wT0, const float* __restrict__ dwT0,
                         const float* __restrict__ wf123,
                         const float* __restrict__ dw0, const float* __restrict__ fbe,
                         float* __restrict__ out)
{
    __shared__ __align__(16) float abuf[PTS * PADA];   // 66,560 B -> 2 blocks/CU
    const int tid = threadIdx.x;
    const int og = tid & 63, pg = tid >> 6;
    const int o0 = og * 4, pbase = pg * 16;
    const int p0 = blockIdx.x * PTS;          // global point base
    const int b  = p0 >> 15;                  // N = 2^15; all 64 pts same batch

    // ---- layer 0 (np-exact, same FP sequence as rounds 6-14) ----
    {
        const float* fb0 = fbe + (size_t)(0 * B + b) * H;
        const float* cb  = coords + (size_t)(p0 + pbase) * 3;
        #pragma unroll
        for (int j = 0; j < 4; ++j) {
            const int o = o0 + j;
            const float wf0 = Wf[o * 3 + 0], wf1 = Wf[o * 3 + 1], wf2 = Wf[o * 3 + 2];
            const float* dwo = dw0 + ((size_t)b * H + o) * 3;
            const float dd0 = dwo[0], dd1 = dwo[1], dd2 = dwo[2];
            const float bo = bf[o], fo = fb0[o];
            for (int k = 0; k < 16; ++k) {
                const float x0 = cb[k * 3 + 0];
                const float x1 = cb[k * 3 + 1];
                const float x2 = cb[k * 3 + 2];
                float lin = 0.f;
                lin = fmaf(x0, wf0, lin);
                lin = fmaf(x1, wf1, lin);
                lin = fmaf(x2, wf2, lin);
                lin = lin + bo;
                float dl = 0.f;
                dl = fmaf(x0, dd0, dl);
                dl = fmaf(x1, dd1, dl);
                dl = fmaf(x2, dd2, dl);
                float z = (lin + dl) + fo;
                abuf[(pbase + k) * PADA + o] = npsinf(30.0f * z);
            }
        }
    }
    // no barrier: h0 reads only this wave's rows

    // ---- h0: np-exact dual GEMM, two 8-point passes ----
    {
        const float4* Wt4 = (const float4*)wT0;
        const float4* Dt4 = (const float4*)(dwT0 + (size_t)b * H * H);
        const float* be  = bh;                               // bh[0][:]
        const float* fbl = fbe + (size_t)(1 * B + b) * H;
        const float4 bo4 = *(const float4*)(be + o0);
        const float4 fo4 = *(const float4*)(fbl + o0);
        const float bo[4] = {bo4.x, bo4.y, bo4.z, bo4.w};
        const float fo[4] = {fo4.x, fo4.y, fo4.z, fo4.w};

        for (int kh = 0; kh < 2; ++kh) {
            const int kb = pbase + kh * 8;
            float lacc[4][8], eacc[4][8];
            #pragma unroll
            for (int j = 0; j < 4; ++j)
                #pragma unroll
                for (int k = 0; k < 8; ++k) { lacc[j][k] = 0.f; eacc[j][k] = 0.f; }

            for (int i0 = 0; i0 < H; i0 += 4) {
                float4 w4[4], d4[4];
                #pragma unroll
                for (int ii = 0; ii < 4; ++ii) {
                    w4[ii] = Wt4[(size_t)(i0 + ii) * 64 + og];
                    d4[ii] = Dt4[(size_t)(i0 + ii) * 64 + og];
                }
                #pragma unroll
                for (int k = 0; k < 8; ++k) {
                    const float4 av = *(const float4*)(&abuf[(kb + k) * PADA + i0]);
                    #pragma unroll
                    for (int ii = 0; ii < 4; ++ii) {   // i ASCENDING per (n,o)
                        const float ai = (&av.x)[ii];
                        #pragma unroll
                        for (int j = 0; j < 4; ++j) {
                            lacc[j][k] = fmaf(ai, (&w4[ii].x)[j], lacc[j][k]);
                            eacc[j][k] = fmaf(ai, (&d4[ii].x)[j], eacc[j][k]);
                        }
                    }
                }
            }
            #pragma unroll
            for (int k = 0; k < 8; ++k) {
                float4 rv;
                #pragma unroll
                for (int j = 0; j < 4; ++j) {
                    float z = ((lacc[j][k] + bo[j]) + eacc[j][k]) + fo[j];
                    (&rv.x)[j] = sinh32(30.0f * z);
                }
                *(float4*)(&abuf[(kb + k) * PADA + o0]) = rv;
            }
        }
    }

    // ---- h1, h2, h3: folded single GEMM, 16 points each ----
    for (int lf = 0; lf < 3; ++lf) {
        const float4* Ft4 = (const float4*)(wf123 + (size_t)(lf * B + b) * H * H);
        const float* be  = bh + (size_t)(lf + 1) * H;
        const float* fbl = fbe + (size_t)((lf + 2) * B + b) * H;
        const float4 bo4 = *(const float4*)(be + o0);
        const float4 fo4 = *(const float4*)(fbl + o0);
        const float bo[4] = {bo4.x, bo4.y, bo4.z, bo4.w};
        const float fo[4] = {fo4.x, fo4.y, fo4.z, fo4.w};

        float lacc[4][16];
        #pragma unroll
        for (int j = 0; j < 4; ++j)
            #pragma unroll
            for (int k = 0; k < 16; ++k) lacc[j][k] = 0.f;

        for (int i0 = 0; i0 < H; i0 += 4) {
            float4 w4[4];
            #pragma unroll
            for (int ii = 0; ii < 4; ++ii)
                w4[ii] = Ft4[(size_t)(i0 + ii) * 64 + og];
            #pragma unroll
            for (int k = 0; k < 16; ++k) {
                const float4 av = *(const float4*)(&abuf[(pbase + k) * PADA + i0]);
                #pragma unroll
                for (int ii = 0; ii < 4; ++ii) {       // i ASCENDING per (n,o)
                    const float ai = (&av.x)[ii];
                    #pragma unroll
                    for (int j = 0; j < 4; ++j)
                        lacc[j][k] = fmaf(ai, (&w4[ii].x)[j], lacc[j][k]);
                }
            }
        }
        #pragma unroll
        for (int k = 0; k < 16; ++k) {
            float4 rv;
            #pragma unroll
            for (int j = 0; j < 4; ++j) {
                float z = (lacc[j][k] + bo[j]) + fo[j];   // folded: linf ~ lin+delta
                (&rv.x)[j] = sinh32(30.0f * z);
            }
            *(float4*)(&abuf[(pbase + k) * PADA + o0]) = rv;
        }
    }

    // ---- final projection (own rows: n = tid>>2 in [pbase, pbase+16)) ----
    {
        const int n = tid >> 2, q = tid & 3;
        const float* ar = abuf + n * PADA + q * 64;
        const float* wl = Wl + q * 64;
        float s = 0.f;
        #pragma unroll 16
        for (int t = 0; t < 64; ++t) s = fmaf(ar[t], wl[t], s);
        s += __shfl_xor(s, 1);
        s += __shfl_xor(s, 2);
        if (q == 0) out[p0 + n] = s + bl[0];
    }
}

// ---------------------------------------------------------------------------
extern "C" void kernel_launch(void* const* d_in, const int* in_sizes, int n_in,
                              void* d_out, int out_size, void* d_ws, size_t ws_size,
                              hipStream_t stream)
{
    const float* coords = (const float*)d_in[0];
    const float* lat    = (const float*)d_in[1];
    const float* Wf     = (const float*)d_in[2];
    const float* bf     = (const float*)d_in[3];
    const float* Wh     = (const float*)d_in[4];
    const float* bh     = (const float*)d_in[5];
    const float* Wl     = (const float*)d_in[6];
    const float* bl     = (const float*)d_in[7];
    const float* U      = (const float*)d_in[8];
    const float* V0     = (const float*)d_in[9];
    const float* Vh     = (const float*)d_in[10];
    const float* HB     = (const float*)d_in[11];

    float* ws    = (float*)d_ws;   // ~8.7 MB
    float* dwT0  = ws + OFS_DWT0;
    float* wf123 = ws + OFS_WF123;
    float* wT0   = ws + OFS_WT0;
    float* dw0   = ws + OFS_DW0;
    float* fbe   = ws + OFS_FBE;

    precomp_np<<<NHID * B + B + B, H, 0, stream>>>(lat, U, V0, Vh, Wh, HB,
                                                   dwT0, wf123, dw0, fbe);
    transposeW<<<H, H, 0, stream>>>(Wh, wT0);
    siren_np<<<(B * N) / PTS, BLOCK, 0, stream>>>(coords, Wf, bf, bh, Wl, bl,
                                                  wT0, dwT0, wf123, dw0, fbe,
                                                  (float*)d_out);
}